// Round 2
// baseline (832.917 us; speedup 1.0000x reference)
//
#include <hip/hip_runtime.h>
#include <math.h>

// DequantAddResidualRMSNormQuant: T=16384 tokens, H=4096 hidden.
//  out0 = clip(rint(res_new * rsqrt(mean(res_new^2)+eps) * weight), -128, 127)  (int8, stored f32)
//  out1 = res_new = residual + x_i32 * (scale[t] * dequant_scale)               (f32)
// d_out = [out0 (T*H floats) | out1 (T*H floats)]
//
// Correctness: harness ref is numpy float64 and the int8 round makes matching
// binary — so the WHOLE chain is computed in f64 (round-1 f32 path gave absmax
// exactly 1.0 = boundary flips). f64 cost ~0.4 GFLOP total: still HBM-bound.
// Memory: 1.07 GB traffic -> ~190 us floor at ~5.7 TB/s.

constexpr int TPB = 256;          // 4 waves
constexpr int HID = 4096;
constexpr int VPT = HID / (4 * TPB);  // float4 chunks per thread = 4

__global__ __launch_bounds__(TPB)
void drrq_kernel(const int4* __restrict__ x,
                 const float4* __restrict__ res_in,
                 const float* __restrict__ scale,
                 const float4* __restrict__ weight,
                 const float* __restrict__ dqs,
                 float4* __restrict__ out_q,
                 float4* __restrict__ out_res)
{
    const int row = blockIdx.x;
    const int tid = threadIdx.x;

    // per-token combined dequant scale, f64 like the np ref: scale[:,None]*dequant_scale
    const double s = (double)scale[row] * (double)dqs[0];

    const size_t rowoff = (size_t)row * (HID / 4);
    const int4*   xr  = x       + rowoff;
    const float4* rr  = res_in  + rowoff;
    float4*       qr  = out_q   + rowoff;
    float4*       orr = out_res + rowoff;

    double v[VPT * 4];   // res_new in f64: 32 VGPRs
    double ss = 0.0;

#pragma unroll
    for (int k = 0; k < VPT; ++k) {
        const int idx = tid + k * TPB;          // lane-contiguous -> coalesced
        const int4   xi = xr[idx];
        const float4 rv = rr[idx];
        double t0 = (double)rv.x + (double)xi.x * s;
        double t1 = (double)rv.y + (double)xi.y * s;
        double t2 = (double)rv.z + (double)xi.z * s;
        double t3 = (double)rv.w + (double)xi.w * s;
        v[k * 4 + 0] = t0; v[k * 4 + 1] = t1;
        v[k * 4 + 2] = t2; v[k * 4 + 3] = t3;
        float4 o;
        o.x = (float)t0; o.y = (float)t1; o.z = (float)t2; o.w = (float)t3;
        orr[idx] = o;                           // res_new written once, from pass 1
        ss += t0 * t0 + t1 * t1 + t2 * t2 + t3 * t3;
    }

    // wave (64-lane) reduction, then cross-wave via LDS
#pragma unroll
    for (int off = 32; off >= 1; off >>= 1)
        ss += __shfl_down(ss, off, 64);

    __shared__ double red[TPB / 64];
    if ((tid & 63) == 0) red[tid >> 6] = ss;
    __syncthreads();

    double tot = red[0];
#pragma unroll
    for (int w = 1; w < TPB / 64; ++w) tot += red[w];

    const double var = tot * (1.0 / HID);       // /4096 is exact (pow2)
    const double inv = 1.0 / sqrt(var + 1e-6);  // f64 rsqrt path like np ref

#pragma unroll
    for (int k = 0; k < VPT; ++k) {
        const int idx = tid + k * TPB;
        const float4 w4 = weight[idx];          // 16 KiB, L2-resident across blocks
        float4 q;
        // normed = (res_new * inv) * weight  -- same association as reference
        q.x = (float)fmin(fmax(rint(v[k*4+0] * inv * (double)w4.x), -128.0), 127.0);
        q.y = (float)fmin(fmax(rint(v[k*4+1] * inv * (double)w4.y), -128.0), 127.0);
        q.z = (float)fmin(fmax(rint(v[k*4+2] * inv * (double)w4.z), -128.0), 127.0);
        q.w = (float)fmin(fmax(rint(v[k*4+3] * inv * (double)w4.w), -128.0), 127.0);
        qr[idx] = q;
    }
}

extern "C" void kernel_launch(void* const* d_in, const int* in_sizes, int n_in,
                              void* d_out, int out_size, void* d_ws, size_t ws_size,
                              hipStream_t stream) {
    const int*   x        = (const int*)d_in[0];
    const float* residual = (const float*)d_in[1];
    const float* scale    = (const float*)d_in[2];
    const float* weight   = (const float*)d_in[3];
    const float* dqs      = (const float*)d_in[4];

    const int T = in_sizes[2];   // per-token scale length = 16384

    float* out_q   = (float*)d_out;
    float* out_res = (float*)d_out + (size_t)T * HID;

    drrq_kernel<<<dim3(T), dim3(TPB), 0, stream>>>(
        (const int4*)x, (const float4*)residual, scale,
        (const float4*)weight, dqs,
        (float4*)out_q, (float4*)out_res);
}